// Round 5
// baseline (243.338 us; speedup 1.0000x reference)
//
#include <hip/hip_runtime.h>
#include <hip/hip_fp16.h>

// Problem constants: B=2, CIN=32, COUT=64, K=9, H=256, W=512, OH=256, OW=512
#define HW_IN   131072
#define W_IN    512
#define H_IN    256
#define HW_OUT  131072
#define CIN     32
#define COUT    64
#define KK      9
#define BB      2

typedef _Float16 hf2 __attribute__((ext_vector_type(2)));
typedef _Float16 hf4 __attribute__((ext_vector_type(4)));
typedef _Float16 hf8 __attribute__((ext_vector_type(8)));
typedef float f32x4 __attribute__((ext_vector_type(4)));

static __device__ __forceinline__ hf8 u4h(uint4 u) {
  return __builtin_bit_cast(hf8, u);
}

// ---------------------------------------------------------------------------
// Kernel 1: transpose x (B,CIN,H*W) fp32 -> xt (H*W, B, CIN) f16, via LDS.
// Costs ~5us (R3 single-dispatch run proved the ~85-95us per-round residual
// is FIXED harness overhead, not this kernel). 1KB-contiguous plane-row
// reads, LDS turn, 1KB-contiguous record stores.
// ---------------------------------------------------------------------------
__global__ __launch_bounds__(256) void transpose_lds(
    const float* __restrict__ x, _Float16* __restrict__ xt) {
  __shared__ _Float16 lt[64][260];   // 33.3 KB, row stride 520B
  int t = threadIdx.x;
  int wave = t >> 6, lane = t & 63;
  int hwbase = blockIdx.x * 256;

#pragma unroll
  for (int i = 0; i < 16; ++i) {
    int p = i * 4 + wave;
    f32x4 v = *((const f32x4*)(x + (size_t)p * HW_IN + hwbase) + lane);
    hf4 h;
    h[0] = (_Float16)v[0]; h[1] = (_Float16)v[1];
    h[2] = (_Float16)v[2]; h[3] = (_Float16)v[3];
    *(hf4*)&lt[p][lane * 4] = h;
  }
  __syncthreads();

  int gg  = t & 7;
  int hl0 = t >> 3;
#pragma unroll
  for (int j = 0; j < 8; ++j) {
    int hwl = hl0 + j * 32;
    hf8 h;
#pragma unroll
    for (int c = 0; c < 8; ++c) h[c] = lt[gg * 8 + c][hwl];
    *(hf8*)(xt + (size_t)(hwbase + hwl) * 64 + gg * 8) = h;
  }
}

// ---------------------------------------------------------------------------
// Kernel 2: batch-paired gather + MFMA (R4 inner loop), R5 occupancy fix.
// R4 evidence says latency-bound, not BW-bound: batch pairing cut bytes
// 1.73x but time only 1.49x (achieved BW DROPPED 3.62->3.13 TB/s despite
// bigger 256B chunks) -- the real change was waves halving 16384->8192, i.e.
// MLP halved. Little's law: 3.2 TB/s x ~375ns needs ~4.7KB/CU in flight;
// at 16 waves/CU we sit at the edge.
// Fix: 1024-thread blocks (16 waves) share ONE 36KB weight stage ->
// 2 blocks/CU x 16 waves = 32 waves/CU (100%), LDS 72KB/CU < 160KB,
// VGPR 60 <= 64 budget of __launch_bounds__(1024,8). Inner loop identical.
// Epilogue stores nontemporal: out is 67MB write-once; keep it from
// evicting xt from L2.
// ---------------------------------------------------------------------------
__global__ __launch_bounds__(1024, 8) void mapped_conv_mfma(
    const _Float16* __restrict__ xt,
    const float* __restrict__ weight,   // [COUT][CIN][KK] fp32
    const float* __restrict__ bias,     // [COUT]
    const float* __restrict__ sm,       // [HW_OUT][KK][2] fp32
    float* __restrict__ out) {          // [BB][COUT][HW_OUT] fp32
  __shared__ __align__(16) _Float16 w_lds[KK * COUT * CIN];  // 36 KB

  int t = threadIdx.x;
  // Stage weights: w_lds[(k*64 + o)*32 + c] = W[o][c][k] as f16.
  for (int j = t; j < COUT * CIN * KK; j += 1024) {
    unsigned ju = (unsigned)j;
    unsigned o  = ju / 288u;
    unsigned rr = ju % 288u;
    unsigned c  = rr / 9u;
    unsigned k  = rr % 9u;
    w_lds[(k * 64u + o) * 32u + c] = (_Float16)weight[ju];
  }
  __syncthreads();

  int wave = t >> 6;      // 0..15
  int lane = t & 63;
  int m    = lane & 15;   // A-row: pixel; B-col: cout within N-tile
  int quad = lane >> 4;   // channel quarter (A) / k-chunk (B) / row group (C)

  int hw_base = blockIdx.x * 256 + wave * 16;     // 512 blocks x 16 waves
  int hw = hw_base + m;

  const uint4* xt4 = (const uint4*)xt;

  f32x4 acc0[4] = {{0.f,0.f,0.f,0.f},{0.f,0.f,0.f,0.f},
                   {0.f,0.f,0.f,0.f},{0.f,0.f,0.f,0.f}};
  f32x4 acc1[4] = {{0.f,0.f,0.f,0.f},{0.f,0.f,0.f,0.f},
                   {0.f,0.f,0.f,0.f},{0.f,0.f,0.f,0.f}};

  const float* smp = sm + (size_t)hw * (KK * 2);
  const uint4* wbl = (const uint4*)w_lds + (size_t)(m * 4 + quad);

#pragma unroll 2
  for (int k = 0; k < KK; ++k) {
    float sx = smp[k * 2 + 0];
    float sy = smp[k * 2 + 1];
    float bxf = floorf(sx), byf = floorf(sy);
    float fx = sx - bxf, fy = sy - byf;
    int ix0 = (int)bxf, iy0 = (int)byf;
    int ix1 = min(ix0 + 1, W_IN - 1);
    int iy1 = min(iy0 + 1, H_IN - 1);
    ix0 = max(min(ix0, W_IN - 1), 0); ix1 = max(ix1, 0);
    iy0 = max(min(iy0, H_IN - 1), 0); iy1 = max(iy1, 0);

    int r00 = (iy0 * W_IN + ix0) * 8;
    int r01 = (iy0 * W_IN + ix1) * 8;
    int r10 = (iy1 * W_IN + ix0) * 8;
    int r11 = (iy1 * W_IN + ix1) * 8;

    // b0 half (granule quad) and b1 half (granule 4+quad) back-to-back:
    // same 128B record; (ix0,ix1) pair makes 2x256B contiguous chunks.
    uint4 v00a = xt4[r00 + quad],     v00b = xt4[r00 + 4 + quad];
    uint4 v01a = xt4[r01 + quad],     v01b = xt4[r01 + 4 + quad];
    uint4 v10a = xt4[r10 + quad],     v10b = xt4[r10 + 4 + quad];
    uint4 v11a = xt4[r11 + quad],     v11b = xt4[r11 + 4 + quad];

    _Float16 w00 = (_Float16)((1.f - fx) * (1.f - fy));
    _Float16 w01 = (_Float16)(fx * (1.f - fy));
    _Float16 w10 = (_Float16)((1.f - fx) * fy);
    _Float16 w11 = (_Float16)(fx * fy);
    hf8 h00 = {w00, w00, w00, w00, w00, w00, w00, w00};
    hf8 h01 = {w01, w01, w01, w01, w01, w01, w01, w01};
    hf8 h10 = {w10, w10, w10, w10, w10, w10, w10, w10};
    hf8 h11 = {w11, w11, w11, w11, w11, w11, w11, w11};

    hf8 a0 = h00 * u4h(v00a) + h01 * u4h(v01a) + h10 * u4h(v10a) + h11 * u4h(v11a);
    hf8 a1 = h00 * u4h(v00b) + h01 * u4h(v01b) + h10 * u4h(v10b) + h11 * u4h(v11b);

    const uint4* wk = wbl + (size_t)k * 256;   // per-k block = 64 o * 4 granules
    hf8 b0 = u4h(wk[0]);
    hf8 b1 = u4h(wk[64]);
    hf8 b2 = u4h(wk[128]);
    hf8 b3 = u4h(wk[192]);

    acc0[0] = __builtin_amdgcn_mfma_f32_16x16x32_f16(a0, b0, acc0[0], 0, 0, 0);
    acc1[0] = __builtin_amdgcn_mfma_f32_16x16x32_f16(a1, b0, acc1[0], 0, 0, 0);
    acc0[1] = __builtin_amdgcn_mfma_f32_16x16x32_f16(a0, b1, acc0[1], 0, 0, 0);
    acc1[1] = __builtin_amdgcn_mfma_f32_16x16x32_f16(a1, b1, acc1[1], 0, 0, 0);
    acc0[2] = __builtin_amdgcn_mfma_f32_16x16x32_f16(a0, b2, acc0[2], 0, 0, 0);
    acc1[2] = __builtin_amdgcn_mfma_f32_16x16x32_f16(a1, b2, acc1[2], 0, 0, 0);
    acc0[3] = __builtin_amdgcn_mfma_f32_16x16x32_f16(a0, b3, acc0[3], 0, 0, 0);
    acc1[3] = __builtin_amdgcn_mfma_f32_16x16x32_f16(a1, b3, acc1[3], 0, 0, 0);
  }

  // Epilogue: lane writes 4 consecutive pixels (rows quad*4..+3) for cout n,
  // both batches, nontemporal (write-once stream; don't evict xt from L2).
  int hw0 = hw_base + quad * 4;
#pragma unroll
  for (int nt = 0; nt < 4; ++nt) {
    int n = nt * 16 + m;
    float bn = bias[n];
    f32x4 v0 = {acc0[nt][0] + bn, acc0[nt][1] + bn,
                acc0[nt][2] + bn, acc0[nt][3] + bn};
    f32x4 v1 = {acc1[nt][0] + bn, acc1[nt][1] + bn,
                acc1[nt][2] + bn, acc1[nt][3] + bn};
    __builtin_nontemporal_store(v0, (f32x4*)(out + (size_t)n * HW_OUT + hw0));
    __builtin_nontemporal_store(v1, (f32x4*)(out + (size_t)(COUT + n) * HW_OUT + hw0));
  }
}

extern "C" void kernel_launch(void* const* d_in, const int* in_sizes, int n_in,
                              void* d_out, int out_size, void* d_ws, size_t ws_size,
                              hipStream_t stream) {
  const float* x  = (const float*)d_in[0];   // [B][CIN][H*W]
  const float* w  = (const float*)d_in[1];   // [COUT][CIN][KK]
  const float* bs = (const float*)d_in[2];   // [COUT]
  const float* sm = (const float*)d_in[3];   // [OH*OW][KK][2]
  float* out = (float*)d_out;                // [B][COUT][OH*OW]
  _Float16* xt = (_Float16*)d_ws;            // 16 MB scratch: (H*W, B, CIN) f16

  transpose_lds<<<dim3(512), dim3(256), 0, stream>>>(x, xt);
  mapped_conv_mfma<<<dim3(512), dim3(1024), 0, stream>>>(xt, w, bs, sm, out);
}

// Round 6
// 188.959 us; speedup vs baseline: 1.2878x; 1.2878x over previous
//
#include <hip/hip_runtime.h>
#include <hip/hip_fp16.h>

// Problem constants: B=2, CIN=32, COUT=64, K=9, H=256, W=512, OH=256, OW=512
#define HW_IN   131072
#define W_IN    512
#define H_IN    256
#define HW_OUT  131072
#define CIN     32
#define COUT    64
#define KK      9
#define BB      2

typedef _Float16 hf2 __attribute__((ext_vector_type(2)));
typedef _Float16 hf4 __attribute__((ext_vector_type(4)));
typedef _Float16 hf8 __attribute__((ext_vector_type(8)));
typedef float f32x4 __attribute__((ext_vector_type(4)));

static __device__ __forceinline__ hf8 u4h(uint4 u) {
  return __builtin_bit_cast(hf8, u);
}

// ---------------------------------------------------------------------------
// Kernel 1: transpose x (B,CIN,H*W) fp32 -> xt (H*W, B, CIN) f16, via LDS.
// ~5us (R3 single-dispatch run proved the ~88-95us per-round residual is
// FIXED harness overhead). 1KB-contiguous plane-row reads, LDS turn,
// 1KB-contiguous record stores.
// ---------------------------------------------------------------------------
__global__ __launch_bounds__(256) void transpose_lds(
    const float* __restrict__ x, _Float16* __restrict__ xt) {
  __shared__ _Float16 lt[64][260];   // 33.3 KB, row stride 520B
  int t = threadIdx.x;
  int wave = t >> 6, lane = t & 63;
  int hwbase = blockIdx.x * 256;

#pragma unroll
  for (int i = 0; i < 16; ++i) {
    int p = i * 4 + wave;
    f32x4 v = *((const f32x4*)(x + (size_t)p * HW_IN + hwbase) + lane);
    hf4 h;
    h[0] = (_Float16)v[0]; h[1] = (_Float16)v[1];
    h[2] = (_Float16)v[2]; h[3] = (_Float16)v[3];
    *(hf4*)&lt[p][lane * 4] = h;
  }
  __syncthreads();

  int gg  = t & 7;
  int hl0 = t >> 3;
#pragma unroll
  for (int j = 0; j < 8; ++j) {
    int hwl = hl0 + j * 32;
    hf8 h;
#pragma unroll
    for (int c = 0; c < 8; ++c) h[c] = lt[gg * 8 + c][hwl];
    *(hf8*)(xt + (size_t)(hwbase + hwl) * 64 + gg * 8) = h;
  }
}

// ---------------------------------------------------------------------------
// Kernel 2: batch-paired gather + MFMA, R6 = R4 config + explicit depth-2
// tap pipeline. R5 proved: more waves/CU raises achieved BW (3.13->3.95
// TB/s) but the 64-VGPR budget destroys load adjacency (FETCH 246->441MB)
// -> 8 waves/SIMD structurally impossible for this load cluster. Instead,
// raise in-flight bytes PER WAVE at 16 waves/CU: double-buffer the 8 corner
// loads (vA/vB), issue tap k+1's loads before tap k's MFMA consumption, so
// 128B/wave stays outstanding through every compute phase (R4's unroll-2
// left ~0 in flight during compute). Budget: 64 buf + 32 acc + ~25 misc
// ~= 120 <= 128 (launch_bounds(256,4)). Stores back to plain f32x4 (R5's
// nontemporal stores doubled WRITE via partial-line bypass).
// ---------------------------------------------------------------------------
__global__ __launch_bounds__(256, 4) void mapped_conv_mfma(
    const _Float16* __restrict__ xt,
    const float* __restrict__ weight,   // [COUT][CIN][KK] fp32
    const float* __restrict__ bias,     // [COUT]
    const float* __restrict__ sm,       // [HW_OUT][KK][2] fp32
    float* __restrict__ out) {          // [BB][COUT][HW_OUT] fp32
  __shared__ __align__(16) _Float16 w_lds[KK * COUT * CIN];  // 36 KB

  int t = threadIdx.x;
  // Stage weights: w_lds[(k*64 + o)*32 + c] = W[o][c][k] as f16.
  for (int j = t; j < COUT * CIN * KK; j += 256) {
    unsigned ju = (unsigned)j;
    unsigned o  = ju / 288u;
    unsigned rr = ju % 288u;
    unsigned c  = rr / 9u;
    unsigned k  = rr % 9u;
    w_lds[(k * 64u + o) * 32u + c] = (_Float16)weight[ju];
  }
  __syncthreads();

  int wave = t >> 6;
  int lane = t & 63;
  int m    = lane & 15;   // A-row: pixel; B-col: cout within N-tile
  int quad = lane >> 4;   // channel quarter (A) / k-chunk (B) / row group (C)

  int hw_base = blockIdx.x * 64 + wave * 16;      // 2048 blocks x 4 waves
  int hw = hw_base + m;

  const uint4* xt4 = (const uint4*)xt;

  f32x4 acc0[4] = {{0.f,0.f,0.f,0.f},{0.f,0.f,0.f,0.f},
                   {0.f,0.f,0.f,0.f},{0.f,0.f,0.f,0.f}};
  f32x4 acc1[4] = {{0.f,0.f,0.f,0.f},{0.f,0.f,0.f,0.f},
                   {0.f,0.f,0.f,0.f},{0.f,0.f,0.f,0.f}};

  const float* smp = sm + (size_t)hw * (KK * 2);
  const uint4* wbl = (const uint4*)w_lds + (size_t)(m * 4 + quad);

  uint4 vA[8], vB[8];
  float fxA, fyA, fxB, fyB;

  // Issue tap k's 8 corner loads (b0/b1 halves of 4 records; (ix0,ix1)
  // pairs form 2x256B contiguous chunks) + bilinear fractions.
  auto prep = [&](int k, uint4* v, float& fx, float& fy) {
    float sxv = smp[k * 2 + 0];
    float syv = smp[k * 2 + 1];
    float bxf = floorf(sxv), byf = floorf(syv);
    fx = sxv - bxf; fy = syv - byf;
    int ix0 = (int)bxf, iy0 = (int)byf;
    int ix1 = min(ix0 + 1, W_IN - 1);
    int iy1 = min(iy0 + 1, H_IN - 1);
    ix0 = max(min(ix0, W_IN - 1), 0); ix1 = max(ix1, 0);
    iy0 = max(min(iy0, H_IN - 1), 0); iy1 = max(iy1, 0);
    int r00 = (iy0 * W_IN + ix0) * 8;
    int r01 = (iy0 * W_IN + ix1) * 8;
    int r10 = (iy1 * W_IN + ix0) * 8;
    int r11 = (iy1 * W_IN + ix1) * 8;
    v[0] = xt4[r00 + quad];  v[1] = xt4[r00 + 4 + quad];
    v[2] = xt4[r01 + quad];  v[3] = xt4[r01 + 4 + quad];
    v[4] = xt4[r10 + quad];  v[5] = xt4[r10 + 4 + quad];
    v[6] = xt4[r11 + quad];  v[7] = xt4[r11 + 4 + quad];
  };

  // Blend corners into A-frags and run the 8 MFMAs for tap k.
  auto consume = [&](int k, const uint4* v, float fx, float fy) {
    _Float16 w00 = (_Float16)((1.f - fx) * (1.f - fy));
    _Float16 w01 = (_Float16)(fx * (1.f - fy));
    _Float16 w10 = (_Float16)((1.f - fx) * fy);
    _Float16 w11 = (_Float16)(fx * fy);
    hf8 h00 = {w00, w00, w00, w00, w00, w00, w00, w00};
    hf8 h01 = {w01, w01, w01, w01, w01, w01, w01, w01};
    hf8 h10 = {w10, w10, w10, w10, w10, w10, w10, w10};
    hf8 h11 = {w11, w11, w11, w11, w11, w11, w11, w11};

    hf8 a0 = h00 * u4h(v[0]) + h01 * u4h(v[2]) + h10 * u4h(v[4]) + h11 * u4h(v[6]);
    hf8 a1 = h00 * u4h(v[1]) + h01 * u4h(v[3]) + h10 * u4h(v[5]) + h11 * u4h(v[7]);

    const uint4* wk = wbl + (size_t)k * 256;
    hf8 b0 = u4h(wk[0]);
    hf8 b1 = u4h(wk[64]);
    hf8 b2 = u4h(wk[128]);
    hf8 b3 = u4h(wk[192]);

    acc0[0] = __builtin_amdgcn_mfma_f32_16x16x32_f16(a0, b0, acc0[0], 0, 0, 0);
    acc1[0] = __builtin_amdgcn_mfma_f32_16x16x32_f16(a1, b0, acc1[0], 0, 0, 0);
    acc0[1] = __builtin_amdgcn_mfma_f32_16x16x32_f16(a0, b1, acc0[1], 0, 0, 0);
    acc1[1] = __builtin_amdgcn_mfma_f32_16x16x32_f16(a1, b1, acc1[1], 0, 0, 0);
    acc0[2] = __builtin_amdgcn_mfma_f32_16x16x32_f16(a0, b2, acc0[2], 0, 0, 0);
    acc1[2] = __builtin_amdgcn_mfma_f32_16x16x32_f16(a1, b2, acc1[2], 0, 0, 0);
    acc0[3] = __builtin_amdgcn_mfma_f32_16x16x32_f16(a0, b3, acc0[3], 0, 0, 0);
    acc1[3] = __builtin_amdgcn_mfma_f32_16x16x32_f16(a1, b3, acc1[3], 0, 0, 0);
  };

  // Depth-2 pipeline: prep(k+1) is issued before consume(k), so 8 loads
  // stay in flight through every MFMA phase.
  prep(0, vA, fxA, fyA);
  prep(1, vB, fxB, fyB);
  consume(0, vA, fxA, fyA);
  prep(2, vA, fxA, fyA);
  consume(1, vB, fxB, fyB);
  prep(3, vB, fxB, fyB);
  consume(2, vA, fxA, fyA);
  prep(4, vA, fxA, fyA);
  consume(3, vB, fxB, fyB);
  prep(5, vB, fxB, fyB);
  consume(4, vA, fxA, fyA);
  prep(6, vA, fxA, fyA);
  consume(5, vB, fxB, fyB);
  prep(7, vB, fxB, fyB);
  consume(6, vA, fxA, fyA);
  prep(8, vA, fxA, fyA);
  consume(7, vB, fxB, fyB);
  consume(8, vA, fxA, fyA);

  // Epilogue: lane writes 4 consecutive pixels (rows quad*4..+3) for cout n,
  // both batches. Plain stores (L2 write-combined; NT doubled WRITE in R5).
  int hw0 = hw_base + quad * 4;
#pragma unroll
  for (int nt = 0; nt < 4; ++nt) {
    int n = nt * 16 + m;
    float bn = bias[n];
    float4 v0 = make_float4(acc0[nt][0] + bn, acc0[nt][1] + bn,
                            acc0[nt][2] + bn, acc0[nt][3] + bn);
    float4 v1 = make_float4(acc1[nt][0] + bn, acc1[nt][1] + bn,
                            acc1[nt][2] + bn, acc1[nt][3] + bn);
    *(float4*)(out + (size_t)n * HW_OUT + hw0) = v0;
    *(float4*)(out + (size_t)(COUT + n) * HW_OUT + hw0) = v1;
  }
}

extern "C" void kernel_launch(void* const* d_in, const int* in_sizes, int n_in,
                              void* d_out, int out_size, void* d_ws, size_t ws_size,
                              hipStream_t stream) {
  const float* x  = (const float*)d_in[0];   // [B][CIN][H*W]
  const float* w  = (const float*)d_in[1];   // [COUT][CIN][KK]
  const float* bs = (const float*)d_in[2];   // [COUT]
  const float* sm = (const float*)d_in[3];   // [OH*OW][KK][2]
  float* out = (float*)d_out;                // [B][COUT][OH*OW]
  _Float16* xt = (_Float16*)d_ws;            // 16 MB scratch: (H*W, B, CIN) f16

  transpose_lds<<<dim3(512), dim3(256), 0, stream>>>(x, xt);
  mapped_conv_mfma<<<dim3(2048), dim3(256), 0, stream>>>(xt, w, bs, sm, out);
}